// Round 17
// baseline (312.906 us; speedup 1.0000x reference)
//
#include <hip/hip_runtime.h>
#include <hip/hip_bf16.h>
#include <math.h>

// ---------------- constants ----------------
#define BATCH   16
#define TFRM    4096          // frames per batch (= L)
#define DIM     512
#define NFFT    1024
#define HOP     256
#define PADC    384           // (WIN-HOP)/2
#define MROWS   (BATCH*TFRM)  // 65536
#define OUTLEN  1048576       // per-batch output samples
#define TWO_PI_OVER_N 0.006135923151542565f  // 2*pi/1024
#define INV_TWO_PI    0.15915494309189535f   // 1/(2*pi)
#define EPS0    148           // EPI=0 epilogue LDS row stride (74 words; 4-row step ≡ 8 mod 32)
#define EPS1    68            // EPI=1 epilogue LDS row stride (34 words; 4-row step ≡ 8 mod 32)

typedef __bf16 bf16x8 __attribute__((ext_vector_type(8)));
typedef float  f32x16 __attribute__((ext_vector_type(16)));

__device__ __forceinline__ ushort f2bf(float f) {
  union { float f; unsigned u; } v; v.f = f;
  unsigned u = v.u;
  unsigned r = (u + 0x7FFFu + ((u >> 16) & 1u)) >> 16;
  return (ushort)r;
}
__device__ __forceinline__ float bf2f(ushort h) {
  union { unsigned u; float f; } v; v.u = ((unsigned)h) << 16;
  return v.f;
}
// HW transcendentals (single VALU op each; v_sin/v_cos take revolutions).
__device__ __forceinline__ float fast_sin(float x) { return __builtin_amdgcn_sinf(x * INV_TWO_PI); }
__device__ __forceinline__ float fast_cos(float x) { return __builtin_amdgcn_cosf(x * INV_TWO_PI); }
__device__ __forceinline__ float fast_exp(float x) { return __builtin_amdgcn_exp2f(x * 1.4426950408889634f); }
// lane-xor-1 exchange as a single VALU DPP op (quad_perm [1,0,3,2] = 0xB1).
__device__ __forceinline__ float dpp_xor1(float v) {
  return __int_as_float(__builtin_amdgcn_update_dpp(
      __float_as_int(v), __float_as_int(v), 0xB1, 0xF, 0xF, false));
}

// ---------------- prep: x fp32 -> bf16, fused Nyquist GEMV ----------------
__global__ void k_prep_x(const float* __restrict__ x, const float* __restrict__ W,
                         const float* __restrict__ bias,
                         ushort* __restrict__ xbf, float* __restrict__ s512) {
  const int row  = blockIdx.x * 4 + (threadIdx.x >> 6);
  const int lane = threadIdx.x & 63;
  const float* xr = x + (size_t)row * DIM + lane * 8;
  float4 v0 = *(const float4*)xr;
  float4 v1 = *(const float4*)(xr + 4);
  ushort4 u0, u1;
  u0.x = f2bf(v0.x); u0.y = f2bf(v0.y); u0.z = f2bf(v0.z); u0.w = f2bf(v0.w);
  u1.x = f2bf(v1.x); u1.y = f2bf(v1.y); u1.z = f2bf(v1.z); u1.w = f2bf(v1.w);
  ushort* xo = xbf + (size_t)row * DIM + lane * 8;
  *(ushort4*)xo = u0;
  *(ushort4*)(xo + 4) = u1;
  const float* w0 = W + 512 * DIM + lane * 8;    // mag row k=512
  const float* w1 = W + 1025 * DIM + lane * 8;   // phase row k=512
  float4 a0 = *(const float4*)w0, a1 = *(const float4*)(w0 + 4);
  float4 b0 = *(const float4*)w1, b1 = *(const float4*)(w1 + 4);
  float sm = v0.x*a0.x + v0.y*a0.y + v0.z*a0.z + v0.w*a0.w
           + v1.x*a1.x + v1.y*a1.y + v1.z*a1.z + v1.w*a1.w;
  float sp = v0.x*b0.x + v0.y*b0.y + v0.z*b0.z + v0.w*b0.w
           + v1.x*b1.x + v1.y*b1.y + v1.z*b1.z + v1.w*b1.w;
#pragma unroll
  for (int off = 32; off; off >>= 1) {
    sm += __shfl_down(sm, off);
    sp += __shfl_down(sp, off);
  }
  if (lane == 0) {
    float mag = fminf(fast_exp(sm + bias[512]), 100.0f);
    s512[row] = mag * fast_cos(sp + bias[1025]) * (1.0f / 1024.0f);
  }
}

// ---------------- prep: W fp32 -> bf16 interleaved [1024][512]
// Row j: j=2k -> orig mag row k (k=0..511); j=2k+1 -> orig phase row 513+k.
__global__ void k_prep_w(const float* __restrict__ W, ushort* __restrict__ o) {
  int i = blockIdx.x * 256 + threadIdx.x;          // over 1024*512
  int r = i >> 9;
  int c = i & 511;
  int orig = (r >> 1) + (r & 1) * 513;
  o[i] = f2bf(W[orig * DIM + c]);
}

// ---------------- basis: BasE/BasO [512 rows][512 K] bf16, row r -> n=r+1 ----------------
__global__ void k_basis(ushort* __restrict__ basE, ushort* __restrict__ basO) {
  int r = blockIdx.x;                              // 0..511
  int n = r + 1;
  for (int k = threadIdx.x; k < 512; k += 256) {
    float e, o;
    if (k == 0) { e = 1.0f / 1024.0f; o = 0.0f; }
    else {
      int ph = (k * n) & 1023;                     // exact integer phase reduction
      float ang = (float)ph * TWO_PI_OVER_N;
      e = 2.0f * cosf(ang) * (1.0f / 1024.0f);
      o = 2.0f * sinf(ang) * (1.0f / 1024.0f);
    }
    basE[r * 512 + k] = f2bf(e);
    basO[r * 512 + k] = f2bf(o);
  }
}

// ---------------- GEMM (r16 structure, 32x32x16 MFMA): C[m][n] = sum_k A[m][k]*Bt[n][k]
// 128x128 tile, BK=32, 4 waves (2x2 of 64x64 — each wave 2x2 of 32x32 MFMA tiles).
// vs r16 (16x16x32): per tile per wave 8 MFMA instead of 16 at the same 8 ds_reads and
// the same 64 acc VGPRs — halves MFMA issue pressure (r16: VALUBusy 47% ~ 2x MfmaUtil
// 24% = issue-stream-bound), and the 32x32 shape runs ~15% faster per FLOP at peak
// (m119: 2495 vs 2176 TF). Ring-3 LDS (48 KiB, 3 blocks/CU), prefetch distance 2,
// counted vmcnt(4), granule-XOR swizzle ((row>>1)&3 == (lane>>1)&3 for both shapes),
// XCD-chunked grid, LDS-staged coalesced epilogue (row-step-4-safe strides).
// 32x32x16 fragment mapping: A/B row = lane&31, k-octet = lane>>5 (lane&15/lane>>4
// extension, validated shape family); C/D col=lane&31, row=(reg&3)+8*(reg>>2)+
// 4*(lane>>5) [HW-verified m74/m101].
// nsplit>0: blocks with bid>=nsplit run the (A2,Bt2,C2) problem.
// EPI=1: activation epilogue, de-interleaved (a_k->C, b_k->C2), ldc=512.
// EPI=0: E/O store unshifted; first problem folds (-1)^(i+1)*s512[row]; ldc=512.
template<int EPI>
__global__ __launch_bounds__(256) void k_gemm(const ushort* A, const ushort* A2, int lda,
                                              const ushort* Bt, const ushort* Bt2, int ldb,
                                              ushort* C, ushort* C2, int ldc,
                                              int nbn, int NK, int nsplit,
                                              const float* __restrict__ bias,
                                              const float* __restrict__ s512) {
  __shared__ __align__(16) ushort lds[3][2][128 * 32];   // 48 KiB; reused by epilogue
  const int tid  = threadIdx.x;
  const int cpx  = gridDim.x >> 3;
  int bid  = (blockIdx.x & 7) * cpx + (blockIdx.x >> 3);   // XCD-chunked
  bool second = false;
  if (nsplit > 0 && bid >= nsplit) { second = true; A = A2; Bt = Bt2; C = C2; bid -= nsplit; }
  const int bm   = bid / nbn;
  const int bn   = bid - bm * nbn;
  const int lane = tid & 63;
  const int wv   = tid >> 6;
  const int wr   = (wv >> 1) * 64;
  const int wc   = (wv & 1) * 64;
  const int l31  = lane & 31;
  const int kh   = lane >> 5;                              // k-octet selector (0..1)
  const int rsw  = (lane >> 1) & 3;                        // == (row>>1)&3 for our rows

  f32x16 acc[2][2] = {};

  const int swz = ((tid & 3) ^ ((tid >> 3) & 3)) << 3;     // inverse-swizzled source granule
  auto stage = [&](const ushort* __restrict__ g, int ld, int row0, int k0, ushort* l) {
#pragma unroll
    for (int p = 0; p < 2; ++p) {
      int i = tid + p * 256;
      const ushort* gp = g + (size_t)(row0 + (i >> 2)) * ld + k0 + swz;
      ushort* lp = l + ((i >> 6) << 9);   // wave-uniform LDS base; HW scatters lane*16B
      __builtin_amdgcn_global_load_lds(
          (const __attribute__((address_space(1))) void*)gp,
          (__attribute__((address_space(3))) void*)lp, 16, 0, 0);
    }
  };
  // fragment read: logical granule g = ks*2 + kh at row rowbase+l31, swizzled by rsw
  auto frag = [&](const ushort* lb, int rowbase, int ks) -> bf16x8 {
    const int row = rowbase + l31;
    return *(const bf16x8*)(lb + row * 32 + (((ks * 2 + kh) ^ rsw) << 3));
  };

  // prologue: stage tiles 0 and 1; land tile 0 (tile 1's 4 loads stay in flight)
  stage(A,  lda, bm * 128, 0,  &lds[0][0][0]);
  stage(Bt, ldb, bn * 128, 0,  &lds[0][1][0]);
  stage(A,  lda, bm * 128, 32, &lds[1][0][0]);
  stage(Bt, ldb, bn * 128, 32, &lds[1][1][0]);
  asm volatile("s_waitcnt vmcnt(4)" ::: "memory");
  __syncthreads();

  int sl = 0;                                              // slot of tile t
  for (int t = 0; t < NK; ++t) {
    if (t + 2 < NK) {
      const int psl = (sl >= 1) ? sl - 1 : 2;              // (sl+2)%3
      stage(A,  lda, bm * 128, (t + 2) << 5, &lds[psl][0][0]);
      stage(Bt, ldb, bn * 128, (t + 2) << 5, &lds[psl][1][0]);
    }
    const ushort* lA = &lds[sl][0][0];
    const ushort* lB = &lds[sl][1][0];
    bf16x8 aF[2][2], bF[2][2];                             // [ks][m/n]
#pragma unroll
    for (int ks = 0; ks < 2; ++ks) {
#pragma unroll
      for (int m = 0; m < 2; ++m) aF[ks][m] = frag(lA, wr + m * 32, ks);
#pragma unroll
      for (int n = 0; n < 2; ++n) bF[ks][n] = frag(lB, wc + n * 32, ks);
    }
#pragma unroll
    for (int ks = 0; ks < 2; ++ks)
#pragma unroll
      for (int m = 0; m < 2; ++m)
#pragma unroll
        for (int n = 0; n < 2; ++n)
          acc[m][n] = __builtin_amdgcn_mfma_f32_32x32x16_bf16(aF[ks][m], bF[ks][n],
                                                              acc[m][n], 0, 0, 0);
    if (t + 2 < NK)      asm volatile("s_waitcnt vmcnt(4)" ::: "memory");
    else if (t + 2 == NK) asm volatile("s_waitcnt vmcnt(0)" ::: "memory");
    if (t + 1 < NK) __syncthreads();
    sl = (sl >= 2) ? 0 : sl + 1;
  }

  // ---- epilogue (LDS-staged, coalesced) ----
  // acc[m][n] reg r: local row = wr + m*32 + (r&3) + 8*(r>>2) + 4*kh, col = wc + n*32 + l31.
  ushort* epi = &lds[0][0][0];
  const bool odd = lane & 1;
  __syncthreads();   // all main-loop LDS reads complete everywhere before overwrite

  if constexpr (EPI == 0) {
    // value(col c) = acc + Nyquist fold (first problem): n_st = c+1; c even -> -sv.
#pragma unroll
    for (int m = 0; m < 2; ++m) {
#pragma unroll
      for (int q = 0; q < 4; ++q) {
        const int lrow0 = wr + m * 32 + q * 8 + (kh << 2);
        float4 sv4 = {0.f, 0.f, 0.f, 0.f};
        if (!second) sv4 = *(const float4*)(s512 + bm * 128 + lrow0);
#pragma unroll
        for (int rr = 0; rr < 4; ++rr) {
          const float sv = ((const float*)&sv4)[rr];
          const float par = second ? 0.0f : (odd ? sv : -sv);
          const int lrow = lrow0 + rr;
#pragma unroll
          for (int n = 0; n < 2; ++n) {
            const int c = wc + n * 32 + l31;
            epi[lrow * EPS0 + c] = f2bf(acc[m][n][q * 4 + rr] + par);
          }
        }
      }
    }
    __syncthreads();
#pragma unroll
    for (int i = 0; i < 8; ++i) {
      int row = (tid >> 4) + i * 16;
      int co  = (tid & 15) << 3;
      bf16x8 v = *(const bf16x8*)(epi + row * EPS0 + co);
      *(bf16x8*)(C + (size_t)(bm * 128 + row) * ldc + bn * 128 + co) = v;
    }
  } else {
    // Activation: interleaved cols (2k=mag_k, 2k+1=phase_k); DPP pairs adjacent lanes
    // (col = lane&31 -> lane^1 = col^1).
    ushort* tA = epi;
    ushort* tB = epi + 128 * EPS1;
#pragma unroll
    for (int n = 0; n < 2; ++n) {
      const int cl  = wc + n * 32 + l31;             // local col 0..127
      const int kk  = (bn * 128 + cl) >> 1;          // global k index
      const float bs = bias[odd ? 513 + kk : kk];
      ushort* dst = (odd ? tB : tA);
      const int kkl = cl >> 1;                       // local k 0..63
#pragma unroll
      for (int m = 0; m < 2; ++m)
#pragma unroll
        for (int q = 0; q < 4; ++q)
#pragma unroll
          for (int rr = 0; rr < 4; ++rr) {
            const int lrow = wr + m * 32 + q * 8 + (kh << 2) + rr;
            float v = acc[m][n][q * 4 + rr] + bs;
            float pv = dpp_xor1(v);
            float hm = odd ? pv : v;
            float hp = odd ? v : pv;
            float mag = fminf(fast_exp(hm), 100.0f);
            float outv = odd ? mag * fast_sin(hp) : mag * fast_cos(hp);
            dst[lrow * EPS1 + kkl] = f2bf(outv);
          }
    }
    __syncthreads();
#pragma unroll
    for (int i = 0; i < 4; ++i) {
      int row = (tid >> 3) + i * 32;
      int co  = (tid & 7) << 3;
      size_t go = (size_t)(bm * 128 + row) * ldc + bn * 64 + co;
      bf16x8 va = *(const bf16x8*)(tA + row * EPS1 + co);
      *(bf16x8*)(C + go) = va;
      bf16x8 vb = *(const bf16x8*)(tB + row * EPS1 + co);
      *(bf16x8*)(C2 + go) = vb;
    }
  }
}

// ---------------- overlap-add (4 samples/thread, aligned vector loads) ----------------
// E/O unshifted: E[i] = E_st[i+1], stride 512. frames[n] = win[n]*(E_st[n] -+ O_st[n]);
// n<=512 direct ('-'), n>512 mirrors to 1024-n ('+'). Nyquist pre-folded into E.
// Interior envelope exactly 1.5 (Hann^2 OLA at 75% overlap).
__global__ void k_oa(const ushort* __restrict__ E, const ushort* __restrict__ O,
                     float* __restrict__ out) {
  int u = blockIdx.x * 256 + threadIdx.x;       // 16 * 262144 groups of 4 samples
  int b  = u >> 18;
  int g  = u & 262143;
  int s  = (g << 2) + PADC;
  int t0 = s >> 8;
  int nb = s & 255;                             // multiple of 4
  float acc[4] = {0.f, 0.f, 0.f, 0.f};
  bool interior = (t0 >= 3) && (t0 < TFRM);
  float env[4];
#pragma unroll
  for (int j = 0; j < 4; ++j) env[j] = interior ? 1.5f : 0.0f;
#pragma unroll
  for (int q = 0; q < 4; ++q) {
    int t = t0 - q;
    if (t < 0 || t >= TFRM) continue;
    int n = nb + (q << 8);                      // multiple of 4, in [0, 1020]
    size_t base = ((size_t)(b << 12) + t) << 9; // row * 512
    float w[4];
#pragma unroll
    for (int j = 0; j < 4; ++j) {
      w[j] = 0.5f - 0.5f * __builtin_amdgcn_cosf((float)(n + j) * (1.0f / 1024.0f));
      if (!interior) env[j] += w[j] * w[j];
    }
    float d[4];
    if (n <= 508) {                             // direct: d[j] = E[n+j-1] - O[n+j-1]
      ushort4 e1 = *(const ushort4*)(E + base + n);
      ushort4 o1 = *(const ushort4*)(O + base + n);
      if (n >= 4) {
        ushort4 e0 = *(const ushort4*)(E + base + n - 4);
        ushort4 o0 = *(const ushort4*)(O + base + n - 4);
        d[0] = bf2f(e0.w) - bf2f(o0.w);
      } else d[0] = 0.0f;                       // n==0: w[0]=0 anyway
      d[1] = bf2f(e1.x) - bf2f(o1.x);
      d[2] = bf2f(e1.y) - bf2f(o1.y);
      d[3] = bf2f(e1.z) - bf2f(o1.z);
    } else if (n == 512) {                      // straddle: one aligned load at 508
      ushort4 e = *(const ushort4*)(E + base + 508);
      ushort4 o = *(const ushort4*)(O + base + 508);
      d[0] = bf2f(e.w) - bf2f(o.w);             // O_st[512]=0, sign moot
      d[1] = bf2f(e.z) + bf2f(o.z);
      d[2] = bf2f(e.y) + bf2f(o.y);
      d[3] = bf2f(e.x) + bf2f(o.x);
    } else {                                    // n >= 516 mirror: load at 1020-n
      ushort4 e = *(const ushort4*)(E + base + 1020 - n);
      ushort4 o = *(const ushort4*)(O + base + 1020 - n);
      d[0] = bf2f(e.w) + bf2f(o.w);
      d[1] = bf2f(e.z) + bf2f(o.z);
      d[2] = bf2f(e.y) + bf2f(o.y);
      d[3] = bf2f(e.x) + bf2f(o.x);
    }
#pragma unroll
    for (int j = 0; j < 4; ++j) acc[j] += w[j] * d[j];
  }
  float4 o4;
  o4.x = acc[0] / env[0]; o4.y = acc[1] / env[1];
  o4.z = acc[2] / env[2]; o4.w = acc[3] / env[3];
  *(float4*)(out + (size_t)u * 4) = o4;
}

// ---------------- launch ----------------
extern "C" void kernel_launch(void* const* d_in, const int* in_sizes, int n_in,
                              void* d_out, int out_size, void* d_ws, size_t ws_size,
                              hipStream_t stream) {
  const float* x    = (const float*)d_in[0];
  const float* W    = (const float*)d_in[1];
  const float* bias = (const float*)d_in[2];
  float* out = (float*)d_out;
  char* ws = (char*)d_ws;

  // ws layout (bytes):
  //   [0, 67108864)             xbf bf16 [65536][512] (dead after GEMM1)  ALIASED WITH E
  //   [67108864, 134217728)     h_a bf16 [65536][512]  (a_k = mag*cos)
  //   [134217728, 201326592)    h_b bf16 [65536][512]  (b_k = mag*sin)
  //   [201326592, 268435456)    O  bf16 [65536][512]
  //   [268435456, 269484032)    Wp bf16 [1024][512] (interleaved pairs, no Nyquist)
  //   [269484032, 270008320)    BasE bf16 [512][512]
  //   [270008320, 270532608)    BasO bf16 [512][512]
  //   [270532608, 270794752)    s512 fp32 [65536]
  ushort* xbf  = (ushort*)(ws + 0);
  ushort* Epp  = (ushort*)(ws + 0);
  ushort* h_a  = (ushort*)(ws + 67108864);
  ushort* h_b  = (ushort*)(ws + 134217728);
  ushort* Obuf = (ushort*)(ws + 201326592);
  ushort* Wp   = (ushort*)(ws + 268435456);
  ushort* basE = (ushort*)(ws + 269484032);
  ushort* basO = (ushort*)(ws + 270008320);
  float*  s512 = (float*) (ws + 270532608);

  k_prep_x<<<MROWS / 4, 256, 0, stream>>>(x, W, bias, xbf, s512);
  k_prep_w<<<(1024 * 512) / 256, 256, 0, stream>>>(W, Wp);
  k_basis<<<512, 256, 0, stream>>>(basE, basO);

  // GEMM1 + fused activation: h_a/h_b[65536][512] = act( xbf[65536][512] . Wp^T ), N=1024
  k_gemm<1><<<(MROWS / 128) * 8, 256, 0, stream>>>(
      xbf, nullptr, DIM, Wp, nullptr, DIM, h_a, h_b, 512, 8, 16, 0, bias, nullptr);

  // GEMM2 (fused pair): E = h_a . BasE^T (+Nyquist fold) ; O = h_b . BasO^T
  k_gemm<0><<<2 * (MROWS / 128) * 4, 256, 0, stream>>>(
      h_a, h_b, 512, basE, basO, 512, Epp, Obuf, 512, 4, 16, (MROWS / 128) * 4,
      nullptr, s512);

  // overlap-add, windowing, mirror reconstruction, envelope normalize, crop
  k_oa<<<(BATCH * OUTLEN) / 1024, 256, 0, stream>>>(Epp, Obuf, out);
}

// Round 18
// 304.036 us; speedup vs baseline: 1.0292x; 1.0292x over previous
//
#include <hip/hip_runtime.h>
#include <hip/hip_bf16.h>
#include <math.h>

// ---------------- constants ----------------
#define BATCH   16
#define TFRM    4096          // frames per batch (= L)
#define DIM     512
#define NFFT    1024
#define HOP     256
#define PADC    384           // (WIN-HOP)/2
#define MROWS   (BATCH*TFRM)  // 65536
#define OUTLEN  1048576       // per-batch output samples
#define TWO_PI_OVER_N 0.006135923151542565f  // 2*pi/1024
#define INV_TWO_PI    0.15915494309189535f   // 1/(2*pi)
#define EPS1    68            // GEMM1 epilogue LDS row stride (ushorts)

typedef __bf16 bf16x8 __attribute__((ext_vector_type(8)));
typedef float  f32x16 __attribute__((ext_vector_type(16)));

__device__ __forceinline__ ushort f2bf(float f) {
  union { float f; unsigned u; } v; v.f = f;
  unsigned u = v.u;
  unsigned r = (u + 0x7FFFu + ((u >> 16) & 1u)) >> 16;
  return (ushort)r;
}
__device__ __forceinline__ float bf2f(ushort h) {
  union { unsigned u; float f; } v; v.u = ((unsigned)h) << 16;
  return v.f;
}
// HW transcendentals (single VALU op each; v_sin/v_cos take revolutions).
__device__ __forceinline__ float fast_sin(float x) { return __builtin_amdgcn_sinf(x * INV_TWO_PI); }
__device__ __forceinline__ float fast_cos(float x) { return __builtin_amdgcn_cosf(x * INV_TWO_PI); }
__device__ __forceinline__ float fast_exp(float x) { return __builtin_amdgcn_exp2f(x * 1.4426950408889634f); }
// lane-xor-1 exchange as a single VALU DPP op (quad_perm [1,0,3,2] = 0xB1).
__device__ __forceinline__ float dpp_xor1(float v) {
  return __int_as_float(__builtin_amdgcn_update_dpp(
      __float_as_int(v), __float_as_int(v), 0xB1, 0xF, 0xF, false));
}
__device__ __forceinline__ f32x16 MF(bf16x8 a, bf16x8 b, f32x16 c) {
  return __builtin_amdgcn_mfma_f32_32x32x16_bf16(a, b, c, 0, 0, 0);
}

// ---------------- prep: x fp32 -> bf16, fused Nyquist GEMV ----------------
__global__ void k_prep_x(const float* __restrict__ x, const float* __restrict__ W,
                         const float* __restrict__ bias,
                         ushort* __restrict__ xbf, float* __restrict__ s512) {
  const int row  = blockIdx.x * 4 + (threadIdx.x >> 6);
  const int lane = threadIdx.x & 63;
  const float* xr = x + (size_t)row * DIM + lane * 8;
  float4 v0 = *(const float4*)xr;
  float4 v1 = *(const float4*)(xr + 4);
  ushort4 u0, u1;
  u0.x = f2bf(v0.x); u0.y = f2bf(v0.y); u0.z = f2bf(v0.z); u0.w = f2bf(v0.w);
  u1.x = f2bf(v1.x); u1.y = f2bf(v1.y); u1.z = f2bf(v1.z); u1.w = f2bf(v1.w);
  ushort* xo = xbf + (size_t)row * DIM + lane * 8;
  *(ushort4*)xo = u0;
  *(ushort4*)(xo + 4) = u1;
  const float* w0 = W + 512 * DIM + lane * 8;    // mag row k=512
  const float* w1 = W + 1025 * DIM + lane * 8;   // phase row k=512
  float4 a0 = *(const float4*)w0, a1 = *(const float4*)(w0 + 4);
  float4 b0 = *(const float4*)w1, b1 = *(const float4*)(w1 + 4);
  float sm = v0.x*a0.x + v0.y*a0.y + v0.z*a0.z + v0.w*a0.w
           + v1.x*a1.x + v1.y*a1.y + v1.z*a1.z + v1.w*a1.w;
  float sp = v0.x*b0.x + v0.y*b0.y + v0.z*b0.z + v0.w*b0.w
           + v1.x*b1.x + v1.y*b1.y + v1.z*b1.z + v1.w*b1.w;
#pragma unroll
  for (int off = 32; off; off >>= 1) {
    sm += __shfl_down(sm, off);
    sp += __shfl_down(sp, off);
  }
  if (lane == 0) {
    float mag = fminf(fast_exp(sm + bias[512]), 100.0f);
    s512[row] = mag * fast_cos(sp + bias[1025]) * (1.0f / 1024.0f);
  }
}

// ---------------- prep: W fp32 -> bf16 interleaved [1024][512]
// Row j: j=2k -> orig mag row k (k=0..511); j=2k+1 -> orig phase row 513+k.
__global__ void k_prep_w(const float* __restrict__ W, ushort* __restrict__ o) {
  int i = blockIdx.x * 256 + threadIdx.x;          // over 1024*512
  int r = i >> 9;
  int c = i & 511;
  int orig = (r >> 1) + (r & 1) * 513;
  o[i] = f2bf(W[orig * DIM + c]);
}

// ---------------- basis: BasE/BasO FRAGMENT-MAJOR for 32x32x16 GEMM2
// frag(rg,t): idx = ((rg*32 + t)*64 + lane)*8 + j holds B[rg*32+(lane&31)][t*16+(lane>>5)*8+j]
// Logical row r -> output sample n = r+1. rg in [0,16), t in [0,32).
__global__ void k_basis(ushort* __restrict__ basE, ushort* __restrict__ basO) {
  int i = blockIdx.x * 256 + threadIdx.x;          // over 512*512
  int j    = i & 7;
  int lane = (i >> 3) & 63;
  int ft   = i >> 9;                               // rg*32 + t
  int t    = ft & 31;
  int rg   = ft >> 5;
  int r    = rg * 32 + (lane & 31);
  int k    = t * 16 + ((lane >> 5) << 3) + j;
  int n    = r + 1;
  float e, o;
  if (k == 0) { e = 1.0f / 1024.0f; o = 0.0f; }
  else {
    int ph = (k * n) & 1023;                       // exact integer phase reduction
    float ang = (float)ph * TWO_PI_OVER_N;
    e = 2.0f * cosf(ang) * (1.0f / 1024.0f);
    o = 2.0f * sinf(ang) * (1.0f / 1024.0f);
  }
  basE[i] = f2bf(e);
  basO[i] = f2bf(o);
}

// ---------------- GEMM1 (r17 structure, 32x32x16): h = act(xbf . Wp^T)
// Unchanged main loop (128x128 tile, BK=32, ring-3 LDS, vmcnt(4), granule-XOR swizzle,
// XCD-chunked grid). Activation epilogue now stores h_a/h_b FRAGMENT-MAJOR:
// frag(rg,t) at ((rg*32+t)*64 + lane)*8 — so GEMM2 can load A operands coalesced
// straight to VGPRs. Derivation: value tA[row][kl] (row=rgl*32+(l&31), kl=tl*16+(l>>5)*8)
// belongs to frag(bm*4+rgl, bn*4+tl) at lane l (lane-in-frag == l exactly).
__global__ __launch_bounds__(256) void k_gemm1(const ushort* __restrict__ A, int lda,
                                               const ushort* __restrict__ Bt, int ldb,
                                               ushort* __restrict__ Ca, ushort* __restrict__ Cb,
                                               int nbn, int NK,
                                               const float* __restrict__ bias) {
  __shared__ __align__(16) ushort lds[3][2][128 * 32];   // 48 KiB; reused by epilogue
  const int tid  = threadIdx.x;
  const int cpx  = gridDim.x >> 3;
  const int bid  = ((int)blockIdx.x & 7) * cpx + ((int)blockIdx.x >> 3);
  const int bm   = bid / nbn;
  const int bn   = bid - bm * nbn;
  const int lane = tid & 63;
  const int wv   = tid >> 6;
  const int wr   = (wv >> 1) * 64;
  const int wc   = (wv & 1) * 64;
  const int l31  = lane & 31;
  const int kh   = lane >> 5;
  const int rsw  = (lane >> 1) & 3;

  f32x16 acc[2][2] = {};

  const int swz = ((tid & 3) ^ ((tid >> 3) & 3)) << 3;
  auto stage = [&](const ushort* __restrict__ g, int ld, int row0, int k0, ushort* l) {
#pragma unroll
    for (int p = 0; p < 2; ++p) {
      int i = tid + p * 256;
      const ushort* gp = g + (size_t)(row0 + (i >> 2)) * ld + k0 + swz;
      ushort* lp = l + ((i >> 6) << 9);
      __builtin_amdgcn_global_load_lds(
          (const __attribute__((address_space(1))) void*)gp,
          (__attribute__((address_space(3))) void*)lp, 16, 0, 0);
    }
  };
  auto frag = [&](const ushort* lb, int rowbase, int ks) -> bf16x8 {
    const int row = rowbase + l31;
    return *(const bf16x8*)(lb + row * 32 + (((ks * 2 + kh) ^ rsw) << 3));
  };

  stage(A,  lda, bm * 128, 0,  &lds[0][0][0]);
  stage(Bt, ldb, bn * 128, 0,  &lds[0][1][0]);
  stage(A,  lda, bm * 128, 32, &lds[1][0][0]);
  stage(Bt, ldb, bn * 128, 32, &lds[1][1][0]);
  asm volatile("s_waitcnt vmcnt(4)" ::: "memory");
  __syncthreads();

  int sl = 0;
  for (int t = 0; t < NK; ++t) {
    if (t + 2 < NK) {
      const int psl = (sl >= 1) ? sl - 1 : 2;
      stage(A,  lda, bm * 128, (t + 2) << 5, &lds[psl][0][0]);
      stage(Bt, ldb, bn * 128, (t + 2) << 5, &lds[psl][1][0]);
    }
    const ushort* lA = &lds[sl][0][0];
    const ushort* lB = &lds[sl][1][0];
    bf16x8 aF[2][2], bF[2][2];
#pragma unroll
    for (int ks = 0; ks < 2; ++ks) {
#pragma unroll
      for (int m = 0; m < 2; ++m) aF[ks][m] = frag(lA, wr + m * 32, ks);
#pragma unroll
      for (int n = 0; n < 2; ++n) bF[ks][n] = frag(lB, wc + n * 32, ks);
    }
#pragma unroll
    for (int ks = 0; ks < 2; ++ks)
#pragma unroll
      for (int m = 0; m < 2; ++m)
#pragma unroll
        for (int n = 0; n < 2; ++n)
          acc[m][n] = MF(aF[ks][m], bF[ks][n], acc[m][n]);
    if (t + 2 < NK)      asm volatile("s_waitcnt vmcnt(4)" ::: "memory");
    else if (t + 2 == NK) asm volatile("s_waitcnt vmcnt(0)" ::: "memory");
    if (t + 1 < NK) __syncthreads();
    sl = (sl >= 2) ? 0 : sl + 1;
  }

  // ---- epilogue: activation into LDS (de-interleaved), fragment-major store ----
  ushort* epi = &lds[0][0][0];
  ushort* tA = epi;
  ushort* tB = epi + 128 * EPS1;
  const bool odd = lane & 1;
  __syncthreads();
#pragma unroll
  for (int n = 0; n < 2; ++n) {
    const int cl  = wc + n * 32 + l31;
    const int kk  = (bn * 128 + cl) >> 1;
    const float bs = bias[odd ? 513 + kk : kk];
    ushort* dst = (odd ? tB : tA);
    const int kkl = cl >> 1;
#pragma unroll
    for (int m = 0; m < 2; ++m)
#pragma unroll
      for (int q = 0; q < 4; ++q)
#pragma unroll
        for (int rr = 0; rr < 4; ++rr) {
          const int lrow = wr + m * 32 + q * 8 + (kh << 2) + rr;
          float v = acc[m][n][q * 4 + rr] + bs;
          float pv = dpp_xor1(v);
          float hm = odd ? pv : v;
          float hp = odd ? v : pv;
          float mag = fminf(fast_exp(hm), 100.0f);
          float outv = odd ? mag * fast_sin(hp) : mag * fast_cos(hp);
          dst[lrow * EPS1 + kkl] = f2bf(outv);
        }
  }
  __syncthreads();
  const int tl = tid >> 6;
  const int l  = tid & 63;
#pragma unroll
  for (int it = 0; it < 4; ++it) {
    const int row = it * 32 + (l & 31);
    const int kl  = tl * 16 + ((l >> 5) << 3);
    size_t go = (((size_t)(bm * 4 + it) * 32 + bn * 4 + tl) * 64 + l) * 8;
    *(bf16x8*)(Ca + go) = *(const bf16x8*)(tA + row * EPS1 + kl);
    *(bf16x8*)(Cb + go) = *(const bf16x8*)(tB + row * EPS1 + kl);
  }
}

// ---------------- GEMM2: zero-LDS, zero-barrier, per-wave 64x64 tiles ----------------
// E = h_a . BasE^T (+ Nyquist fold), O = h_b . BasO^T, both M=65536 N=512 K=512.
// Each wave independent: A/B fragments loaded global->VGPR from FRAGMENT-MAJOR
// layouts (64 lanes x 16B contiguous = coalesced 1KB), double-buffered E/O sets,
// untracked inline-asm loads + manual vmcnt ladder (+sched_barrier(0), rule #18).
// FIFO: prologue 8 loads, vmcnt(4) lands t=0. Iter: MFMA E(t); LDG E(t+2); vmcnt(4)
// lands O(t+1); MFMA O(t+1); LDG O(t+3); vmcnt(4) lands E(t+2). Tail: vmcnt(0).
// No __syncthreads: epilogue LDS region is per-wave private (same-wave lgkm ordering).
__global__ __launch_bounds__(256) void k_gemm2(const ushort* __restrict__ hA,
                                               const ushort* __restrict__ hB,
                                               const ushort* __restrict__ basE,
                                               const ushort* __restrict__ basO,
                                               ushort* __restrict__ E, ushort* __restrict__ O,
                                               const float* __restrict__ s512) {
  __shared__ __align__(16) ushort lds[4][64 * 72];   // per-wave private 9KB regions
  const int tid  = threadIdx.x;
  const int cpx  = gridDim.x >> 3;
  const int bid  = ((int)blockIdx.x & 7) * cpx + ((int)blockIdx.x >> 3);   // XCD-chunked
  const int wv   = tid >> 6;
  const int lane = tid & 63;
  const int wid  = bid * 4 + wv;                 // 0..16383
  const bool isO = wid >= 8192;
  const int w    = wid & 8191;
  const int mt   = w >> 3;                       // M-tile 0..1023 (64 rows)
  const int nt   = w & 7;                        // N-tile 0..7 (64 cols)
  const ushort* A  = isO ? hB : hA;
  const ushort* B  = isO ? basO : basE;
  ushort* Cp = isO ? O : E;

  // frag(rg,t) base pointers; per k-tile t the offset advances by 64*8 = 512 ushorts.
  const ushort* pa0 = A + (((size_t)(mt * 2) * 32) * 64 + lane) * 8;
  const ushort* pa1 = pa0 + (size_t)32 * 64 * 8;
  const ushort* pb0 = B + (((size_t)(nt * 2) * 32) * 64 + lane) * 8;
  const ushort* pb1 = pb0 + (size_t)32 * 64 * 8;

  f32x16 acc[2][2] = {};
  bf16x8 aE0, aE1, bE0, bE1, aO0, aO1, bO0, bO1;   // named dbuf sets (rule #20)

#define LDG2(dst, ptr) asm volatile("global_load_dwordx4 %0, %1, off" : "=v"(dst) : "v"(ptr))
#define LOADSET_E(toff) { LDG2(aE0, pa0 + (toff) * 512); LDG2(aE1, pa1 + (toff) * 512); \
                          LDG2(bE0, pb0 + (toff) * 512); LDG2(bE1, pb1 + (toff) * 512); }
#define LOADSET_O(toff) { LDG2(aO0, pa0 + (toff) * 512); LDG2(aO1, pa1 + (toff) * 512); \
                          LDG2(bO0, pb0 + (toff) * 512); LDG2(bO1, pb1 + (toff) * 512); }

  LOADSET_E(0);
  LOADSET_O(1);
  asm volatile("s_waitcnt vmcnt(4)" ::: "memory");
  __builtin_amdgcn_sched_barrier(0);

#pragma unroll
  for (int t = 0; t < 32; t += 2) {
    acc[0][0] = MF(aE0, bE0, acc[0][0]); acc[0][1] = MF(aE0, bE1, acc[0][1]);
    acc[1][0] = MF(aE1, bE0, acc[1][0]); acc[1][1] = MF(aE1, bE1, acc[1][1]);
    if (t + 2 < 32) { LOADSET_E(t + 2); asm volatile("s_waitcnt vmcnt(4)" ::: "memory"); }
    else            { asm volatile("s_waitcnt vmcnt(0)" ::: "memory"); }
    __builtin_amdgcn_sched_barrier(0);
    acc[0][0] = MF(aO0, bO0, acc[0][0]); acc[0][1] = MF(aO0, bO1, acc[0][1]);
    acc[1][0] = MF(aO1, bO0, acc[1][0]); acc[1][1] = MF(aO1, bO1, acc[1][1]);
    if (t + 2 < 32) {
      LOADSET_O(t + 3);
      asm volatile("s_waitcnt vmcnt(4)" ::: "memory");
      __builtin_amdgcn_sched_barrier(0);
    }
  }

  // ---- epilogue (per-wave private LDS; no barriers) ----
  ushort* wl = &lds[wv][0];
  const int kh  = lane >> 5;
  const int l31 = lane & 31;
  const bool odd = lane & 1;
#pragma unroll
  for (int m = 0; m < 2; ++m)
#pragma unroll
    for (int q = 0; q < 4; ++q) {
      const int rowb = m * 32 + q * 8 + (kh << 2);
      float4 sv4 = {0.f, 0.f, 0.f, 0.f};
      if (!isO) sv4 = *(const float4*)(s512 + mt * 64 + rowb);
#pragma unroll
      for (int rr = 0; rr < 4; ++rr) {
        const float sv = ((const float*)&sv4)[rr];
        const float par = isO ? 0.0f : (odd ? sv : -sv);
#pragma unroll
        for (int n = 0; n < 2; ++n)
          wl[(rowb + rr) * 72 + n * 32 + l31] = f2bf(acc[m][n][q * 4 + rr] + par);
      }
    }
  // same-wave LDS write->read ordering via lgkmcnt (compiler-inserted)
#pragma unroll
  for (int it = 0; it < 8; ++it) {
    const int lrow = (lane >> 3) + it * 8;
    const int lcol = (lane & 7) << 3;
    bf16x8 v = *(const bf16x8*)(wl + lrow * 72 + lcol);
    *(bf16x8*)(Cp + ((size_t)(mt * 64 + lrow) << 9) + nt * 64 + lcol) = v;
  }
#undef LDG2
#undef LOADSET_E
#undef LOADSET_O
}

// ---------------- overlap-add (4 samples/thread, aligned vector loads) ----------------
// E/O unshifted: E[i] = E_st[i+1], stride 512. frames[n] = win[n]*(E_st[n] -+ O_st[n]);
// n<=512 direct ('-'), n>512 mirrors to 1024-n ('+'). Nyquist pre-folded into E.
__global__ void k_oa(const ushort* __restrict__ E, const ushort* __restrict__ O,
                     float* __restrict__ out) {
  int u = blockIdx.x * 256 + threadIdx.x;       // 16 * 262144 groups of 4 samples
  int b  = u >> 18;
  int g  = u & 262143;
  int s  = (g << 2) + PADC;
  int t0 = s >> 8;
  int nb = s & 255;                             // multiple of 4
  float acc[4] = {0.f, 0.f, 0.f, 0.f};
  bool interior = (t0 >= 3) && (t0 < TFRM);
  float env[4];
#pragma unroll
  for (int j = 0; j < 4; ++j) env[j] = interior ? 1.5f : 0.0f;
#pragma unroll
  for (int q = 0; q < 4; ++q) {
    int t = t0 - q;
    if (t < 0 || t >= TFRM) continue;
    int n = nb + (q << 8);                      // multiple of 4, in [0, 1020]
    size_t base = ((size_t)(b << 12) + t) << 9; // row * 512
    float w[4];
#pragma unroll
    for (int j = 0; j < 4; ++j) {
      w[j] = 0.5f - 0.5f * __builtin_amdgcn_cosf((float)(n + j) * (1.0f / 1024.0f));
      if (!interior) env[j] += w[j] * w[j];
    }
    float d[4];
    if (n <= 508) {                             // direct: d[j] = E[n+j-1] - O[n+j-1]
      ushort4 e1 = *(const ushort4*)(E + base + n);
      ushort4 o1 = *(const ushort4*)(O + base + n);
      if (n >= 4) {
        ushort4 e0 = *(const ushort4*)(E + base + n - 4);
        ushort4 o0 = *(const ushort4*)(O + base + n - 4);
        d[0] = bf2f(e0.w) - bf2f(o0.w);
      } else d[0] = 0.0f;                       // n==0: w[0]=0 anyway
      d[1] = bf2f(e1.x) - bf2f(o1.x);
      d[2] = bf2f(e1.y) - bf2f(o1.y);
      d[3] = bf2f(e1.z) - bf2f(o1.z);
    } else if (n == 512) {                      // straddle: one aligned load at 508
      ushort4 e = *(const ushort4*)(E + base + 508);
      ushort4 o = *(const ushort4*)(O + base + 508);
      d[0] = bf2f(e.w) - bf2f(o.w);             // O_st[512]=0, sign moot
      d[1] = bf2f(e.z) + bf2f(o.z);
      d[2] = bf2f(e.y) + bf2f(o.y);
      d[3] = bf2f(e.x) + bf2f(o.x);
    } else {                                    // n >= 516 mirror: load at 1020-n
      ushort4 e = *(const ushort4*)(E + base + 1020 - n);
      ushort4 o = *(const ushort4*)(O + base + 1020 - n);
      d[0] = bf2f(e.w) + bf2f(o.w);
      d[1] = bf2f(e.z) + bf2f(o.z);
      d[2] = bf2f(e.y) + bf2f(o.y);
      d[3] = bf2f(e.x) + bf2f(o.x);
    }
#pragma unroll
    for (int j = 0; j < 4; ++j) acc[j] += w[j] * d[j];
  }
  float4 o4;
  o4.x = acc[0] / env[0]; o4.y = acc[1] / env[1];
  o4.z = acc[2] / env[2]; o4.w = acc[3] / env[3];
  *(float4*)(out + (size_t)u * 4) = o4;
}

// ---------------- launch ----------------
extern "C" void kernel_launch(void* const* d_in, const int* in_sizes, int n_in,
                              void* d_out, int out_size, void* d_ws, size_t ws_size,
                              hipStream_t stream) {
  const float* x    = (const float*)d_in[0];
  const float* W    = (const float*)d_in[1];
  const float* bias = (const float*)d_in[2];
  float* out = (float*)d_out;
  char* ws = (char*)d_ws;

  // ws layout (bytes):
  //   [0, 67108864)             xbf bf16 [65536][512] (dead after GEMM1)  ALIASED WITH E
  //   [67108864, 134217728)     h_a bf16 fragment-major [2048 rg][32 t][64][8]
  //   [134217728, 201326592)    h_b bf16 fragment-major
  //   [201326592, 268435456)    O  bf16 [65536][512] row-major
  //   [268435456, 269484032)    Wp bf16 [1024][512] row-major (interleaved pairs)
  //   [269484032, 270008320)    BasE bf16 fragment-major [16 rg][32 t][64][8]
  //   [270008320, 270532608)    BasO bf16 fragment-major
  //   [270532608, 270794752)    s512 fp32 [65536]
  ushort* xbf  = (ushort*)(ws + 0);
  ushort* Epp  = (ushort*)(ws + 0);
  ushort* h_a  = (ushort*)(ws + 67108864);
  ushort* h_b  = (ushort*)(ws + 134217728);
  ushort* Obuf = (ushort*)(ws + 201326592);
  ushort* Wp   = (ushort*)(ws + 268435456);
  ushort* basE = (ushort*)(ws + 269484032);
  ushort* basO = (ushort*)(ws + 270008320);
  float*  s512 = (float*) (ws + 270532608);

  k_prep_x<<<MROWS / 4, 256, 0, stream>>>(x, W, bias, xbf, s512);
  k_prep_w<<<(1024 * 512) / 256, 256, 0, stream>>>(W, Wp);
  k_basis<<<(512 * 512) / 256, 256, 0, stream>>>(basE, basO);

  // GEMM1 + fused activation, fragment-major h output
  k_gemm1<<<(MROWS / 128) * 8, 256, 0, stream>>>(xbf, DIM, Wp, DIM, h_a, h_b, 8, 16, bias);

  // GEMM2: zero-LDS per-wave tiles; E (+Nyquist fold) and O in one launch
  k_gemm2<<<4096, 256, 0, stream>>>(h_a, h_b, basE, basO, Epp, Obuf, s512);

  // overlap-add, windowing, mirror reconstruction, envelope normalize, crop
  k_oa<<<(BATCH * OUTLEN) / 1024, 256, 0, stream>>>(Epp, Obuf, out);
}